// Round 4
// baseline (9997.392 us; speedup 1.0000x reference)
//
#include <hip/hip_runtime.h>
#include <hip/hip_bf16.h>

#define B_ 32
#define S_ 512
#define V_ 8000
#define I_ 256
#define H_ 512
#define LN_EPS 1e-5f
#define NSL 16          // j-slices == k-slices (32 each)
#define NRG 4           // row groups (8 rows each)
#define NBLK (NSL*NRG)  // 64 blocks

// dynamic-LDS float offsets (total 39336 floats = 157344 B <= 160 KiB)
#define OFF_WREC 0      // [512][32] k-major, quad-XOR swizzle   : 16384
#define OFF_WTR  16384  // [32][516] k-major, padded             : 16512
#define OFF_HBUF 32896  // [8][516]  h_prev per row              : 4128
#define OFF_HT   37024  // [8][33]   phase-A output (local k)    : 264
#define OFF_RED  37288  // [8][8][32] phase-A cross-wave partials: 2048
#define LDS_FLOATS 39336

// ---------------- transpose (for W_in only) ----------------
__global__ void k_transpose(const float* __restrict__ in, float* __restrict__ out,
                            int R, int C) {
    __shared__ float tile[32][33];
    int c0 = blockIdx.x * 32, r0 = blockIdx.y * 32;
    int tx = threadIdx.x, ty = threadIdx.y;  // block (32,8)
#pragma unroll
    for (int i = 0; i < 32; i += 8)
        tile[ty + i][tx] = in[(size_t)(r0 + ty + i) * C + (c0 + tx)];
    __syncthreads();
#pragma unroll
    for (int i = 0; i < 32; i += 8)
        out[(size_t)(c0 + ty + i) * R + (r0 + tx)] = tile[tx][ty + i];
}

// ---------------- embed gather + input projection: Xp[m][j], m = s*B+b ----------------
__global__ __launch_bounds__(512) void k_embed_proj(
        const int* __restrict__ x_idx, const float* __restrict__ emb,
        const float* __restrict__ WinT, const float* __restrict__ b_in,
        float* __restrict__ Xp) {
    __shared__ float e[8][I_];
    const int m0 = blockIdx.x * 8;
    const int t = threadIdx.x;
    {
        int r = t >> 6, i4 = (t & 63) * 4;
        int m = m0 + r;
        int s = m >> 5, b = m & 31;           // m = s*B + b
        int idx = x_idx[b * S_ + s];
        *(float4*)&e[r][i4] = *(const float4*)&emb[(size_t)idx * I_ + i4];
    }
    __syncthreads();
    const int j = t;
    float acc[8];
    const float bj = b_in[j];
#pragma unroll
    for (int r = 0; r < 8; ++r) acc[r] = bj;
    for (int i = 0; i < I_; ++i) {
        float w = WinT[(size_t)i * H_ + j];
#pragma unroll
        for (int r = 0; r < 8; ++r) acc[r] += e[r][i] * w;
    }
#pragma unroll
    for (int r = 0; r < 8; ++r)
        Xp[(size_t)(m0 + r) * H_ + j] = acc[r];
}

// ---------------- fused scan: 64 blocks, ONE global barrier per step ----------------
// block (g, bp): j/k-slice g (32 idx), rows [bp*8, bp*8+8).
// phase A (j-sliced): h_t[R, slice] = tanh(Xp + h_prev @ Wrec_slice^T + brec)
// phase B (k-sliced): u_acc[s%3][R][all j] += h_t[R, slice] @ Wtr[:, slice]^T  (atomicAdd)
// barrier (counter) -> gather full u row, tanh+LN locally (redundant), stage h_new.
__global__ __launch_bounds__(512) void k_scan_fused(
        const float* __restrict__ Xp,
        const float* __restrict__ W_rec, const float* __restrict__ b_rec,
        const float* __restrict__ W_tr,  const float* __restrict__ b_tr,
        const float* __restrict__ gamma, const float* __restrict__ beta,
        float* __restrict__ u_acc, unsigned int* __restrict__ cnt,
        float* __restrict__ hs) {
    extern __shared__ float sm[];
    float* Wr  = sm + OFF_WREC;
    float* Wt  = sm + OFF_WTR;
    float* hb  = sm + OFF_HBUF;
    float* hts = sm + OFF_HT;
    float* red = sm + OFF_RED;

    const int bid = blockIdx.x;
    const int g = bid >> 2, bp = bid & 3;
    const int t = threadIdx.x;
    const int w = t >> 6, l = t & 63;

    // ---- stage weight slices into LDS (once) ----
    // Wr[k][col] = W_rec[g*32+jrel][k], col quad-swizzled: jq' = jq ^ (k&7)
    for (int idx = t; idx < 32 * 512; idx += 512) {
        int jrel = idx >> 9, k = idx & 511;
        float v = W_rec[(size_t)(g * 32 + jrel) * H_ + k];
        int col = (((jrel >> 2) ^ (k & 7)) << 2) | (jrel & 3);
        Wr[k * 32 + col] = v;
    }
    // Wt[kl][j] = W_tr[j][g*32+kl]
    for (int idx = t; idx < 512 * 32; idx += 512) {
        int j = idx >> 5, kl = idx & 31;
        Wt[kl * 516 + j] = W_tr[(size_t)j * H_ + g * 32 + kl];
    }
    // per-thread constant preloads
    const float brj = b_rec[g * 32 + (t & 31)];     // reduce role (t<256)
    float btr8[8], gam8[8], bet8[8];
#pragma unroll
    for (int q = 0; q < 8; ++q) {
        btr8[q] = b_tr[l + 64 * q];
        gam8[q] = gamma[l + 64 * q];
        bet8[q] = beta[l + 64 * q];
    }
    __syncthreads();

    for (int s = 0; s < S_; ++s) {
        // ---------- phase A: partial dots over this wave's k-chunk ----------
        {
            const int rsub = l >> 3, jq = l & 7;
            float a0 = 0, a1 = 0, a2 = 0, a3 = 0;
            if (s > 0) {
                const float* hrow = hb + rsub * 516;
                const int kbase = w * 64;
#pragma unroll 8
                for (int kk = 0; kk < 64; ++kk) {
                    const int k = kbase + kk;
                    const float4 w4 = *(const float4*)&Wr[k * 32 + ((jq ^ (k & 7)) << 2)];
                    const float hv = hrow[k];
                    a0 += hv * w4.x; a1 += hv * w4.y; a2 += hv * w4.z; a3 += hv * w4.w;
                }
            }
            *(float4*)&red[(w * 8 + rsub) * 32 + jq * 4] = make_float4(a0, a1, a2, a3);
        }
        __syncthreads();

        // ---------- reduce across k-groups + tanh -> ht_s ----------
        if (t < 256) {
            const int r = t >> 5, jr = t & 31;
            float sum = 0.f;
#pragma unroll
            for (int kg = 0; kg < 8; ++kg) sum += red[kg * 256 + r * 32 + jr];
            const float xv = Xp[((size_t)s * B_ + bp * 8 + r) * H_ + g * 32 + jr];
            hts[r * 33 + jr] = tanhf(sum + xv + brj);
        }
        __syncthreads();

        // ---------- phase B: k-sliced partials for ALL j, atomicAdd ----------
        {
            const int rsub = l >> 3, jsub = l & 7;
            const int jq0 = w * 16 + jsub, jq1 = jq0 + 8;
            const float* hrow = hts + rsub * 33;
            float b0 = 0, b1 = 0, b2 = 0, b3 = 0, b4 = 0, b5 = 0, b6 = 0, b7 = 0;
#pragma unroll 4
            for (int kl = 0; kl < 32; ++kl) {
                const float hv = hrow[kl];
                const float4 wa = *(const float4*)&Wt[kl * 516 + jq0 * 4];
                const float4 wb = *(const float4*)&Wt[kl * 516 + jq1 * 4];
                b0 += hv * wa.x; b1 += hv * wa.y; b2 += hv * wa.z; b3 += hv * wa.w;
                b4 += hv * wb.x; b5 += hv * wb.y; b6 += hv * wb.z; b7 += hv * wb.w;
            }
            float* ua = u_acc + ((size_t)(s % 3) * B_ + bp * 8 + rsub) * H_;
            atomicAdd(&ua[jq0 * 4 + 0], b0);
            atomicAdd(&ua[jq0 * 4 + 1], b1);
            atomicAdd(&ua[jq0 * 4 + 2], b2);
            atomicAdd(&ua[jq0 * 4 + 3], b3);
            atomicAdd(&ua[jq1 * 4 + 0], b4);
            atomicAdd(&ua[jq1 * 4 + 1], b5);
            atomicAdd(&ua[jq1 * 4 + 2], b6);
            atomicAdd(&ua[jq1 * 4 + 3], b7);
        }
        __syncthreads();                       // drain vmcnt before arrival

        // ---------- single global barrier (counter) ----------
        if (t == 0) {
            __hip_atomic_fetch_add(cnt, 1u, __ATOMIC_RELEASE, __HIP_MEMORY_SCOPE_AGENT);
            const unsigned target = (unsigned)NBLK * (unsigned)(s + 1);
            while (__hip_atomic_load(cnt, __ATOMIC_ACQUIRE, __HIP_MEMORY_SCOPE_AGENT) < target)
                __builtin_amdgcn_s_sleep(1);
        }
        __syncthreads();

        // ---------- zero the (s+2)%3 buffer slice (race-free: first reused at s+2) ----
        if (t < 256) {
            const int r = t >> 5, jr = t & 31;
            __hip_atomic_store(
                &u_acc[((size_t)((s + 2) % 3) * B_ + bp * 8 + r) * H_ + g * 32 + jr],
                0.0f, __ATOMIC_RELAXED, __HIP_MEMORY_SCOPE_AGENT);
        }

        // ---------- gather full u row, tanh + LN (redundant), stage h_new ----------
        {
            const int r = w;                   // wave = row
            const float* ua = u_acc + ((size_t)(s % 3) * B_ + bp * 8 + r) * H_;
            float uv[8], s1 = 0.f, s2 = 0.f;
#pragma unroll
            for (int q = 0; q < 8; ++q) {
                const float p = __hip_atomic_load(&ua[l + 64 * q],
                                   __ATOMIC_RELAXED, __HIP_MEMORY_SCOPE_AGENT);
                const float u = tanhf(p + btr8[q]);
                uv[q] = u; s1 += u; s2 += u * u;
            }
#pragma unroll
            for (int off = 1; off < 64; off <<= 1) {
                s1 += __shfl_xor(s1, off);
                s2 += __shfl_xor(s2, off);
            }
            const float mean = s1 * (1.0f / H_);
            const float rs = rsqrtf(s2 * (1.0f / H_) - mean * mean + LN_EPS);
            float* hsrow = hs + ((size_t)s * B_ + bp * 8 + r) * H_;
#pragma unroll
            for (int q = 0; q < 8; ++q) {
                const float hn = (uv[q] - mean) * rs * gam8[q] + bet8[q];
                const int j = l + 64 * q;
                hb[r * 516 + j] = hn;
                if ((j >> 5) == g) hsrow[j] = hn;   // distributed hs write
            }
        }
        __syncthreads();                       // hb ready for next phase A
    }
}

// ---------------- output GEMM: y[b,s,v] = hs[m,:] . W_out[v,:] + b_out[v] ----------------
__global__ __launch_bounds__(256) void k_out_gemm(
        const float* __restrict__ hs, const float* __restrict__ W_out,
        const float* __restrict__ b_out, float* __restrict__ y) {
    __shared__ float Ast[16][68];
    __shared__ float Bs[16][68];

    const int v0 = blockIdx.x * 64;
    const int m0 = blockIdx.y * 64;
    const int t  = threadIdx.x;
    const int tx = t & 15, ty = t >> 4;

    float acc[4][4] = {};

    for (int k0 = 0; k0 < H_; k0 += 16) {
        const int kk = t & 15;
        const int mm = (t >> 4) << 2;
#pragma unroll
        for (int q = 0; q < 4; ++q)
            Ast[kk][mm + q] = hs[(size_t)(m0 + mm + q) * H_ + k0 + kk];
#pragma unroll
        for (int q = 0; q < 4; ++q)
            Bs[kk][mm + q] = W_out[(size_t)(v0 + mm + q) * H_ + k0 + kk];
        __syncthreads();

#pragma unroll
        for (int k = 0; k < 16; ++k) {
            float4 a4 = *(const float4*)&Ast[k][ty * 4];
            float4 b4 = *(const float4*)&Bs[k][tx * 4];
            float a[4] = {a4.x, a4.y, a4.z, a4.w};
            float bb[4] = {b4.x, b4.y, b4.z, b4.w};
#pragma unroll
            for (int i = 0; i < 4; ++i)
#pragma unroll
                for (int jq = 0; jq < 4; ++jq)
                    acc[i][jq] += a[i] * bb[jq];
        }
        __syncthreads();
    }

#pragma unroll
    for (int i = 0; i < 4; ++i) {
        int m = m0 + ty * 4 + i;
        int s = m >> 5, b = m & 31;
        size_t row = ((size_t)b * S_ + s) * V_;
        int v = v0 + tx * 4;
        float4 rr;
        rr.x = acc[i][0] + b_out[v + 0];
        rr.y = acc[i][1] + b_out[v + 1];
        rr.z = acc[i][2] + b_out[v + 2];
        rr.w = acc[i][3] + b_out[v + 3];
        *(float4*)&y[row + v] = rr;
    }
}

extern "C" void kernel_launch(void* const* d_in, const int* in_sizes, int n_in,
                              void* d_out, int out_size, void* d_ws, size_t ws_size,
                              hipStream_t stream) {
    const int*   x_idx = (const int*)d_in[0];
    const float* emb   = (const float*)d_in[1];
    const float* W_in  = (const float*)d_in[2];
    const float* b_in  = (const float*)d_in[3];
    const float* W_rec = (const float*)d_in[4];
    const float* b_rec = (const float*)d_in[5];
    const float* W_tr  = (const float*)d_in[6];
    const float* b_tr  = (const float*)d_in[7];
    const float* gamma = (const float*)d_in[8];
    const float* beta  = (const float*)d_in[9];
    const float* W_out = (const float*)d_in[10];
    const float* b_out = (const float*)d_in[11];
    float* y  = (float*)d_out;
    float* ws = (float*)d_ws;

    // workspace layout (floats), total ~16.96M floats = 64.7 MB
    float* WinT  = ws;                          // 131072
    float* Xp    = ws + 131072;                 // [S*B][H] = 8388608
    float* hs    = ws + 8519680;                // [S*B][H] = 8388608
    float* u_acc = ws + 16908288;               // [3][B][H] = 49152
    unsigned int* cnt = (unsigned int*)(ws + 16957440);

    // allow >64KB dynamic LDS for the scan kernel (idempotent, host-side)
    (void)hipFuncSetAttribute((const void*)k_scan_fused,
                              hipFuncAttributeMaxDynamicSharedMemorySize,
                              LDS_FLOATS * 4);

    dim3 tb(32, 8);
    k_transpose<<<dim3(I_ / 32, H_ / 32), tb, 0, stream>>>(W_in, WinT, H_, I_);

    k_embed_proj<<<(B_ * S_) / 8, 512, 0, stream>>>(x_idx, emb, WinT, b_in, Xp);

    hipMemsetAsync(u_acc, 0, 3 * B_ * H_ * sizeof(float), stream);
    hipMemsetAsync(cnt, 0, sizeof(unsigned int), stream);

    k_scan_fused<<<NBLK, 512, LDS_FLOATS * 4, stream>>>(
        Xp, W_rec, b_rec, W_tr, b_tr, gamma, beta, u_acc, cnt, hs);

    k_out_gemm<<<dim3(V_ / 64, (B_ * S_) / 64), 256, 0, stream>>>(hs, W_out, b_out, y);
}

// Round 5
// 4807.543 us; speedup vs baseline: 2.0795x; 2.0795x over previous
//
#include <hip/hip_runtime.h>
#include <hip/hip_bf16.h>

#define B_ 32
#define S_ 512
#define V_ 8000
#define I_ 256
#define H_ 512
#define LN_EPS 1e-5f
#define NSL 16          // j-slices of 32
#define NBP 8           // row-groups of 4
#define NBLK 128

// dynamic-LDS float offsets (total 39208 floats = 156832 B <= 160 KiB)
#define OFF_WR  0       // [32][516] W_rec slice, row-major k-contig
#define OFF_WT  16512   // [32][516] W_tr slice
#define OFF_HB  33024   // [4][516]  h_prev rows
#define OFF_HTF 35088   // [4][516]  gathered h_t / u rows
#define OFF_RED 37152   // [16][4][32] k-chunk partials
#define OFF_LN  39200   // [4][2] mean/rstd
#define LDSF    39208

static __device__ __forceinline__ unsigned short f2bf(float x) {
    __hip_bfloat16 h = __float2bfloat16(x);
    return *reinterpret_cast<unsigned short*>(&h);
}

// ---------------- transpose (W_in only) ----------------
__global__ void k_transpose(const float* __restrict__ in, float* __restrict__ out,
                            int R, int C) {
    __shared__ float tile[32][33];
    int c0 = blockIdx.x * 32, r0 = blockIdx.y * 32;
    int tx = threadIdx.x, ty = threadIdx.y;  // block (32,8)
#pragma unroll
    for (int i = 0; i < 32; i += 8)
        tile[ty + i][tx] = in[(size_t)(r0 + ty + i) * C + (c0 + tx)];
    __syncthreads();
#pragma unroll
    for (int i = 0; i < 32; i += 8)
        out[(size_t)(c0 + ty + i) * R + (r0 + tx)] = tile[tx][ty + i];
}

// ---------------- fp32 -> bf16 convert (W_out) ----------------
__global__ __launch_bounds__(256) void k_cvt_bf16(const float* __restrict__ in,
                                                  unsigned short* __restrict__ out, int n4) {
    for (int i = blockIdx.x * 256 + threadIdx.x; i < n4; i += gridDim.x * 256) {
        float4 v = ((const float4*)in)[i];
        ushort4 o;
        o.x = f2bf(v.x); o.y = f2bf(v.y); o.z = f2bf(v.z); o.w = f2bf(v.w);
        ((ushort4*)out)[i] = o;
    }
}

// ---------------- embed gather + input projection: Xp[m][j], m = s*B+b ----------------
__global__ __launch_bounds__(512) void k_embed_proj(
        const int* __restrict__ x_idx, const float* __restrict__ emb,
        const float* __restrict__ WinT, const float* __restrict__ b_in,
        float* __restrict__ Xp) {
    __shared__ float e[8][I_];
    const int m0 = blockIdx.x * 8;
    const int t = threadIdx.x;
    {
        int r = t >> 6, i4 = (t & 63) * 4;
        int m = m0 + r;
        int s = m >> 5, b = m & 31;
        int idx = x_idx[b * S_ + s];
        *(float4*)&e[r][i4] = *(const float4*)&emb[(size_t)idx * I_ + i4];
    }
    __syncthreads();
    const int j = t;
    float acc[8];
    const float bj = b_in[j];
#pragma unroll
    for (int r = 0; r < 8; ++r) acc[r] = bj;
    for (int i = 0; i < I_; ++i) {
        float w = WinT[(size_t)i * H_ + j];
#pragma unroll
        for (int r = 0; r < 8; ++r) acc[r] += e[r][i] * w;
    }
#pragma unroll
    for (int r = 0; r < 8; ++r)
        Xp[(size_t)(m0 + r) * H_ + j] = acc[r];
}

// ---------------- LDS-resident distributed scan ----------------
// 128 blocks x 512 thr. block (g,bp): j-slice g (32 j), rows bp*4..bp*4+3.
// Both W slices in LDS. Per step: phase A (j-sliced, vs h_prev) -> barrier ->
// gather h_t -> phase B (j-sliced trunk) -> barrier -> gather u -> redundant LN.
__global__ __launch_bounds__(512) void k_scan_lds(
        const float* __restrict__ Xp,
        const float* __restrict__ W_rec, const float* __restrict__ b_rec,
        const float* __restrict__ W_tr,  const float* __restrict__ b_tr,
        const float* __restrict__ gamma, const float* __restrict__ beta,
        float* __restrict__ ht_pub, float* __restrict__ u_pub,
        unsigned int* __restrict__ flags, unsigned short* __restrict__ hsB) {
    extern __shared__ float sm[];
    float* Wr  = sm + OFF_WR;
    float* Wt  = sm + OFF_WT;
    float* hb  = sm + OFF_HB;
    float* htf = sm + OFF_HTF;
    float* red = sm + OFF_RED;
    float* lnst = sm + OFF_LN;

    const int bid = blockIdx.x;
    const int g = bid >> 3, bp = bid & 7;     // same-bp groups share bid%8 (XCD heuristic)
    const int t = threadIdx.x;
    const int j = t & 31, kc = t >> 5;        // compute role
    const int kb = t & 127, rr = t >> 7;      // LN-stage role

    // stage weight slices into LDS once
    for (int idx = t; idx < 32 * 512; idx += 512) {
        int jj = idx >> 9, k = idx & 511;
        Wr[jj * 516 + k] = W_rec[(size_t)(g * 32 + jj) * H_ + k];
        Wt[jj * 516 + k] = W_tr[(size_t)(g * 32 + jj) * H_ + k];
    }
    const float brj = b_rec[g * 32 + j];
    const float btj = b_tr[g * 32 + j];
    float g4[4], be4[4];
#pragma unroll
    for (int q = 0; q < 4; ++q) {
        g4[q]  = gamma[kb + 128 * q];
        be4[q] = beta[kb + 128 * q];
    }
    __syncthreads();

    for (int s = 0; s < S_; ++s) {
        // prefetch Xp for reduce role
        float xv = 0.f;
        if (t < 128) xv = Xp[((size_t)s * B_ + bp * 4 + (t >> 5)) * H_ + g * 32 + (t & 31)];

        // ---- phase A partials: acc[r] = sum_{k in kc-chunk} h_prev[r][k]*Wrec[j][k]
        {
            float a0 = 0, a1 = 0, a2 = 0, a3 = 0;
            if (s > 0) {
                const int kbase = kc * 32;
#pragma unroll
                for (int i = 0; i < 8; ++i) {
                    const int k4 = kbase + i * 4;
                    const float4 w4 = *(const float4*)&Wr[j * 516 + k4];
                    const float4 h0 = *(const float4*)&hb[0 * 516 + k4];
                    const float4 h1 = *(const float4*)&hb[1 * 516 + k4];
                    const float4 h2 = *(const float4*)&hb[2 * 516 + k4];
                    const float4 h3 = *(const float4*)&hb[3 * 516 + k4];
                    a0 += h0.x * w4.x + h0.y * w4.y + h0.z * w4.z + h0.w * w4.w;
                    a1 += h1.x * w4.x + h1.y * w4.y + h1.z * w4.z + h1.w * w4.w;
                    a2 += h2.x * w4.x + h2.y * w4.y + h2.z * w4.z + h2.w * w4.w;
                    a3 += h3.x * w4.x + h3.y * w4.y + h3.z * w4.z + h3.w * w4.w;
                }
            }
            red[kc * 128 + 0 * 32 + j] = a0;
            red[kc * 128 + 1 * 32 + j] = a1;
            red[kc * 128 + 2 * 32 + j] = a2;
            red[kc * 128 + 3 * 32 + j] = a3;
        }
        __syncthreads();
        if (t < 128) {
            const int r2 = t >> 5, j2 = t & 31;
            float sum = 0.f;
#pragma unroll
            for (int c = 0; c < 16; ++c) sum += red[c * 128 + r2 * 32 + j2];
            float ht = tanhf(sum + xv + brj);
            __hip_atomic_store(&ht_pub[(bp * 4 + r2) * H_ + g * 32 + j2], ht,
                               __ATOMIC_RELAXED, __HIP_MEMORY_SCOPE_AGENT);
        }
        __syncthreads();
        if (t == 0)
            __hip_atomic_store(&flags[bid * 16], 2u * s + 1,
                               __ATOMIC_RELEASE, __HIP_MEMORY_SCOPE_AGENT);
        if (t < NSL)
            while (__hip_atomic_load(&flags[(bp * 16 + t) * 16],
                       __ATOMIC_RELAXED, __HIP_MEMORY_SCOPE_AGENT) < 2u * s + 1)
                __builtin_amdgcn_s_sleep(1);
        __syncthreads();
        __builtin_amdgcn_sched_barrier(0);
        // gather full h_t rows
#pragma unroll
        for (int q = 0; q < 4; ++q) {
            int idx = t + q * 512;
            int r3 = idx >> 9, k = idx & 511;
            htf[r3 * 516 + k] = __hip_atomic_load(&ht_pub[(bp * 4 + r3) * H_ + k],
                                   __ATOMIC_RELAXED, __HIP_MEMORY_SCOPE_AGENT);
        }
        __syncthreads();

        // ---- phase B partials (trunk)
        {
            float a0 = 0, a1 = 0, a2 = 0, a3 = 0;
            const int kbase = kc * 32;
#pragma unroll
            for (int i = 0; i < 8; ++i) {
                const int k4 = kbase + i * 4;
                const float4 w4 = *(const float4*)&Wt[j * 516 + k4];
                const float4 h0 = *(const float4*)&htf[0 * 516 + k4];
                const float4 h1 = *(const float4*)&htf[1 * 516 + k4];
                const float4 h2 = *(const float4*)&htf[2 * 516 + k4];
                const float4 h3 = *(const float4*)&htf[3 * 516 + k4];
                a0 += h0.x * w4.x + h0.y * w4.y + h0.z * w4.z + h0.w * w4.w;
                a1 += h1.x * w4.x + h1.y * w4.y + h1.z * w4.z + h1.w * w4.w;
                a2 += h2.x * w4.x + h2.y * w4.y + h2.z * w4.z + h2.w * w4.w;
                a3 += h3.x * w4.x + h3.y * w4.y + h3.z * w4.z + h3.w * w4.w;
            }
            red[kc * 128 + 0 * 32 + j] = a0;
            red[kc * 128 + 1 * 32 + j] = a1;
            red[kc * 128 + 2 * 32 + j] = a2;
            red[kc * 128 + 3 * 32 + j] = a3;
        }
        __syncthreads();
        if (t < 128) {
            const int r2 = t >> 5, j2 = t & 31;
            float sum = 0.f;
#pragma unroll
            for (int c = 0; c < 16; ++c) sum += red[c * 128 + r2 * 32 + j2];
            float uv = tanhf(sum + btj);
            __hip_atomic_store(&u_pub[(bp * 4 + r2) * H_ + g * 32 + j2], uv,
                               __ATOMIC_RELAXED, __HIP_MEMORY_SCOPE_AGENT);
        }
        __syncthreads();
        if (t == 0)
            __hip_atomic_store(&flags[bid * 16], 2u * s + 2,
                               __ATOMIC_RELEASE, __HIP_MEMORY_SCOPE_AGENT);
        if (t < NSL)
            while (__hip_atomic_load(&flags[(bp * 16 + t) * 16],
                       __ATOMIC_RELAXED, __HIP_MEMORY_SCOPE_AGENT) < 2u * s + 2)
                __builtin_amdgcn_s_sleep(1);
        __syncthreads();
        __builtin_amdgcn_sched_barrier(0);
        // gather full u rows
#pragma unroll
        for (int q = 0; q < 4; ++q) {
            int idx = t + q * 512;
            int r3 = idx >> 9, k = idx & 511;
            htf[r3 * 516 + k] = __hip_atomic_load(&u_pub[(bp * 4 + r3) * H_ + k],
                                   __ATOMIC_RELAXED, __HIP_MEMORY_SCOPE_AGENT);
        }
        __syncthreads();

        // ---- redundant LN stats (waves 0-3, one row each)
        if (t < 256) {
            const int w = t >> 6, l = t & 63;
            float s1 = 0.f, s2 = 0.f;
#pragma unroll
            for (int q = 0; q < 8; ++q) {
                float u = htf[w * 516 + l + 64 * q];
                s1 += u; s2 += u * u;
            }
#pragma unroll
            for (int off = 32; off >= 1; off >>= 1) {
                s1 += __shfl_xor(s1, off);
                s2 += __shfl_xor(s2, off);
            }
            if (l == 0) {
                float mean = s1 * (1.0f / H_);
                float var  = s2 * (1.0f / H_) - mean * mean;
                lnst[w * 2] = mean;
                lnst[w * 2 + 1] = rsqrtf(var + LN_EPS);
            }
        }
        __syncthreads();

        // ---- apply LN: stage h_new into hb; write own slice of hsB (bf16)
        {
            const float m = lnst[rr * 2], rs = lnst[rr * 2 + 1];
            unsigned short* hrow = &hsB[((size_t)s * B_ + bp * 4 + rr) * H_];
#pragma unroll
            for (int q = 0; q < 4; ++q) {
                const int k = kb + 128 * q;
                float u = htf[rr * 516 + k];
                float hn = (u - m) * rs * g4[q] + be4[q];
                hb[rr * 516 + k] = hn;
                if ((k >> 5) == g) hrow[k] = f2bf(hn);
            }
        }
        __syncthreads();
    }
}

// ---------------- output GEMM (bf16 MFMA): y[b,s,v] = hs[m,:].W_out[v,:] + b_out ----------------
typedef __attribute__((ext_vector_type(8))) short short8;
typedef __attribute__((ext_vector_type(4))) float f32x4;

__global__ __launch_bounds__(256) void k_out_mfma(
        const unsigned short* __restrict__ hsB, const unsigned short* __restrict__ WoB,
        const float* __restrict__ b_out, float* __restrict__ y) {
    __shared__ unsigned short As[128 * 40];   // [m][k32], row stride 40 shorts (80 B)
    __shared__ unsigned short Bs[128 * 40];   // [v][k32]

    const int v0 = blockIdx.x * 128;
    const int m0 = blockIdx.y * 128;
    const int t = threadIdx.x;
    const int l = t & 63, wv = t >> 6;
    const int wm = wv >> 1, wn = wv & 1;      // 2x2 waves, 64x64 each

    f32x4 acc[4][4];
#pragma unroll
    for (int i = 0; i < 4; ++i)
#pragma unroll
        for (int jq = 0; jq < 4; ++jq)
            acc[i][jq] = (f32x4){0.f, 0.f, 0.f, 0.f};

    float bias[4];
#pragma unroll
    for (int ni = 0; ni < 4; ++ni) {
        int v = v0 + wn * 64 + ni * 16 + (l & 15);
        bias[ni] = (v < V_) ? b_out[v] : 0.f;
    }

    for (int k0 = 0; k0 < H_; k0 += 32) {
        __syncthreads();
        for (int c = t; c < 512; c += 256) {
            int row = c >> 2, seg = c & 3;
            *(uint4*)&As[row * 40 + seg * 8] =
                *(const uint4*)&hsB[(size_t)(m0 + row) * H_ + k0 + seg * 8];
            int vr = v0 + row; if (vr > V_ - 1) vr = V_ - 1;
            *(uint4*)&Bs[row * 40 + seg * 8] =
                *(const uint4*)&WoB[(size_t)vr * H_ + k0 + seg * 8];
        }
        __syncthreads();

        short8 af[4], bf[4];
#pragma unroll
        for (int i = 0; i < 4; ++i) {
            af[i] = *(short8*)&As[(wm * 64 + i * 16 + (l & 15)) * 40 + (l >> 4) * 8];
            bf[i] = *(short8*)&Bs[(wn * 64 + i * 16 + (l & 15)) * 40 + (l >> 4) * 8];
        }
#pragma unroll
        for (int mi = 0; mi < 4; ++mi)
#pragma unroll
            for (int ni = 0; ni < 4; ++ni)
                acc[mi][ni] = __builtin_amdgcn_mfma_f32_16x16x32_bf16(
                    af[mi], bf[ni], acc[mi][ni], 0, 0, 0);
    }

    // store: D row=(l>>4)*4+p (m), col=l&15 (v)
#pragma unroll
    for (int mi = 0; mi < 4; ++mi) {
#pragma unroll
        for (int ni = 0; ni < 4; ++ni) {
            int vcol = v0 + wn * 64 + ni * 16 + (l & 15);
            if (vcol < V_) {
#pragma unroll
                for (int p = 0; p < 4; ++p) {
                    int m = m0 + wm * 64 + mi * 16 + (l >> 4) * 4 + p;
                    int s = m >> 5, b = m & 31;
                    y[((size_t)b * S_ + s) * V_ + vcol] = acc[mi][ni][p] + bias[ni];
                }
            }
        }
    }
}

extern "C" void kernel_launch(void* const* d_in, const int* in_sizes, int n_in,
                              void* d_out, int out_size, void* d_ws, size_t ws_size,
                              hipStream_t stream) {
    const int*   x_idx = (const int*)d_in[0];
    const float* emb   = (const float*)d_in[1];
    const float* W_in  = (const float*)d_in[2];
    const float* b_in  = (const float*)d_in[3];
    const float* W_rec = (const float*)d_in[4];
    const float* b_rec = (const float*)d_in[5];
    const float* W_tr  = (const float*)d_in[6];
    const float* b_tr  = (const float*)d_in[7];
    const float* gamma = (const float*)d_in[8];
    const float* beta  = (const float*)d_in[9];
    const float* W_out = (const float*)d_in[10];
    const float* b_out = (const float*)d_in[11];
    float* y  = (float*)d_out;
    float* ws = (float*)d_ws;

    // workspace layout (float units), total ~14.80M floats = 59.2 MB
    float* WinT = ws;                                   // 131072
    float* Xp   = ws + 131072;                          // 8388608
    unsigned short* hsB = (unsigned short*)(ws + 8519680);   // 16384*512 bf16 = 4194304 fl
    unsigned short* WoB = (unsigned short*)(ws + 12713984);  // 8000*512 bf16  = 2048000 fl
    float* ht_pub = ws + 14761984;                      // 16384
    float* u_pub  = ws + 14778368;                      // 16384
    unsigned int* flags = (unsigned int*)(ws + 14794752);    // 128*16 u32

    (void)hipFuncSetAttribute((const void*)k_scan_lds,
                              hipFuncAttributeMaxDynamicSharedMemorySize,
                              LDSF * 4);

    dim3 tb(32, 8);
    k_transpose<<<dim3(I_ / 32, H_ / 32), tb, 0, stream>>>(W_in, WinT, H_, I_);

    k_cvt_bf16<<<1024, 256, 0, stream>>>(W_out, WoB, V_ * H_ / 4);

    k_embed_proj<<<(B_ * S_) / 8, 512, 0, stream>>>(x_idx, emb, WinT, b_in, Xp);

    hipMemsetAsync(flags, 0, NBLK * 16 * sizeof(unsigned int), stream);

    k_scan_lds<<<NBLK, 512, LDSF * 4, stream>>>(Xp, W_rec, b_rec, W_tr, b_tr,
                                                gamma, beta, ht_pub, u_pub, flags, hsB);

    k_out_mfma<<<dim3((V_ + 127) / 128, (B_ * S_) / 128), 256, 0, stream>>>(
        hsB, WoB, b_out, y);
}

// Round 6
// 4448.717 us; speedup vs baseline: 2.2473x; 1.0807x over previous
//
#include <hip/hip_runtime.h>
#include <hip/hip_bf16.h>

#define B_ 32
#define S_ 512
#define V_ 8000
#define I_ 256
#define H_ 512
#define LN_EPS 1e-5f
#define NSL 16          // j/k-slices of 32
#define NBP 8           // row-groups of 4 rows
#define NBLK 128
#define PHALF (NBP * NSL * 4 * 512)   // one p buffer: 262144 floats

// dynamic-LDS float offsets (total 37284 floats = 149136 B)
#define OFF_WR   0      // [32][516] W_rec slice, j-row k-contig
#define OFF_WT   16512  // [32][516] W_tr^T slice: WtS[kl][j] = W_tr[j][g*32+kl]
#define OFF_HB   33024  // [4][516]  h_prev rows (full H per row)
#define OFF_HTS  35088  // [4][33]   phase-A output h_t (own slice)
#define OFF_RED  35220  // [16][4][32] phase-A k-chunk partials
#define OFF_RED2 37268  // float2[8] LN wave partials
#define LDSF     37284

static __device__ __forceinline__ unsigned short f2bf(float x) {
    __hip_bfloat16 h = __float2bfloat16(x);
    return *reinterpret_cast<unsigned short*>(&h);
}

// ---------------- transpose (W_in only) ----------------
__global__ void k_transpose(const float* __restrict__ in, float* __restrict__ out,
                            int R, int C) {
    __shared__ float tile[32][33];
    int c0 = blockIdx.x * 32, r0 = blockIdx.y * 32;
    int tx = threadIdx.x, ty = threadIdx.y;  // block (32,8)
#pragma unroll
    for (int i = 0; i < 32; i += 8)
        tile[ty + i][tx] = in[(size_t)(r0 + ty + i) * C + (c0 + tx)];
    __syncthreads();
#pragma unroll
    for (int i = 0; i < 32; i += 8)
        out[(size_t)(c0 + ty + i) * R + (r0 + tx)] = tile[tx][ty + i];
}

// ---------------- fp32 -> bf16 convert (W_out) ----------------
__global__ __launch_bounds__(256) void k_cvt_bf16(const float* __restrict__ in,
                                                  unsigned short* __restrict__ out, int n4) {
    for (int i = blockIdx.x * 256 + threadIdx.x; i < n4; i += gridDim.x * 256) {
        float4 v = ((const float4*)in)[i];
        ushort4 o;
        o.x = f2bf(v.x); o.y = f2bf(v.y); o.z = f2bf(v.z); o.w = f2bf(v.w);
        ((ushort4*)out)[i] = o;
    }
}

// ---------------- embed gather + input projection: Xp[m][j], m = s*B+b ----------------
__global__ __launch_bounds__(512) void k_embed_proj(
        const int* __restrict__ x_idx, const float* __restrict__ emb,
        const float* __restrict__ WinT, const float* __restrict__ b_in,
        float* __restrict__ Xp) {
    __shared__ float e[8][I_];
    const int m0 = blockIdx.x * 8;
    const int t = threadIdx.x;
    {
        int r = t >> 6, i4 = (t & 63) * 4;
        int m = m0 + r;
        int s = m >> 5, b = m & 31;
        int idx = x_idx[b * S_ + s];
        *(float4*)&e[r][i4] = *(const float4*)&emb[(size_t)idx * I_ + i4];
    }
    __syncthreads();
    const int j = t;
    float acc[8];
    const float bj = b_in[j];
#pragma unroll
    for (int r = 0; r < 8; ++r) acc[r] = bj;
    for (int i = 0; i < I_; ++i) {
        float w = WinT[(size_t)i * H_ + j];
#pragma unroll
        for (int r = 0; r < 8; ++r) acc[r] += e[r][i] * w;
    }
#pragma unroll
    for (int r = 0; r < 8; ++r)
        Xp[(size_t)(m0 + r) * H_ + j] = acc[r];
}

// ---------------- ONE-barrier distributed scan ----------------
// 128 blocks x 512 thr; bid = bp*16 + g. Block (g,bp): j/k-slice g, rows bp*4..+3.
// Per step: phase A (h_t for own slice) -> phase B (k-slice-g partial of trunk for
// ALL j) -> publish 8KB -> ONE barrier -> gather 16 partials (128KB, LLC) -> sum
// -> tanh+LN redundantly -> h_new kept in LDS. No h/u exchange at all.
__global__ __launch_bounds__(512) void k_scan_1b(
        const float* __restrict__ Xp,
        const float* __restrict__ W_rec, const float* __restrict__ b_rec,
        const float* __restrict__ W_tr,  const float* __restrict__ b_tr,
        const float* __restrict__ gamma, const float* __restrict__ beta,
        float* __restrict__ pP, unsigned int* __restrict__ flags,
        unsigned short* __restrict__ hsB) {
    extern __shared__ float sm[];
    float*  WrS  = sm + OFF_WR;
    float*  WtS  = sm + OFF_WT;
    float*  hb   = sm + OFF_HB;
    float*  hts  = sm + OFF_HTS;
    float*  red  = sm + OFF_RED;
    float2* red2 = (float2*)(sm + OFF_RED2);

    const int bid = blockIdx.x;
    const int bp = bid >> 4, g = bid & 15;    // same-bp blocks consecutive (spread XCDs)
    const int t = threadIdx.x;
    const int j = t & 31, kc = t >> 5;        // phase-A role
    const int rB = t >> 7, jB = (t & 127) << 2;  // phase-B / LN role
    const int wid = t >> 6;

    // stage weight slices into LDS once
    for (int idx = t; idx < 32 * 512; idx += 512) {
        int jj = idx >> 9, k = idx & 511;
        WrS[jj * 516 + k] = W_rec[(size_t)(g * 32 + jj) * H_ + k];
    }
    for (int idx = t; idx < 512 * 32; idx += 512) {
        int jj = idx >> 5, kl = idx & 31;
        WtS[kl * 516 + jj] = W_tr[(size_t)jj * H_ + g * 32 + kl];
    }
    const float brj = b_rec[g * 32 + j];
    const float4 bt4 = *(const float4*)&b_tr[jB];
    const float4 gm4 = *(const float4*)&gamma[jB];
    const float4 be4 = *(const float4*)&beta[jB];
    __syncthreads();

    for (int s = 0; s < S_; ++s) {
        // Xp prefetch for reduce role
        float xv = 0.f;
        if (t < 128) xv = Xp[((size_t)s * B_ + bp * 4 + (t >> 5)) * H_ + g * 32 + (t & 31)];

        // ---- phase A partials: (kc,j) over 32 k for 4 rows ----
        {
            float a0 = 0, a1 = 0, a2 = 0, a3 = 0;
            if (s > 0) {
                const int kbase = kc * 32;
#pragma unroll
                for (int i = 0; i < 8; ++i) {
                    const int k4 = kbase + i * 4;
                    const float4 w4 = *(const float4*)&WrS[j * 516 + k4];
                    const float4 h0 = *(const float4*)&hb[0 * 516 + k4];
                    const float4 h1 = *(const float4*)&hb[1 * 516 + k4];
                    const float4 h2 = *(const float4*)&hb[2 * 516 + k4];
                    const float4 h3 = *(const float4*)&hb[3 * 516 + k4];
                    a0 += h0.x * w4.x + h0.y * w4.y + h0.z * w4.z + h0.w * w4.w;
                    a1 += h1.x * w4.x + h1.y * w4.y + h1.z * w4.z + h1.w * w4.w;
                    a2 += h2.x * w4.x + h2.y * w4.y + h2.z * w4.z + h2.w * w4.w;
                    a3 += h3.x * w4.x + h3.y * w4.y + h3.z * w4.z + h3.w * w4.w;
                }
            }
            red[kc * 128 + 0 * 32 + j] = a0;
            red[kc * 128 + 1 * 32 + j] = a1;
            red[kc * 128 + 2 * 32 + j] = a2;
            red[kc * 128 + 3 * 32 + j] = a3;
        }
        __syncthreads();
        if (t < 128) {
            const int r2 = t >> 5, j2 = t & 31;
            float sum = 0.f;
#pragma unroll
            for (int c = 0; c < 16; ++c) sum += red[c * 128 + r2 * 32 + j2];
            hts[r2 * 33 + j2] = tanhf(sum + xv + brj);
        }
        __syncthreads();

        // ---- phase B: k-slice-g partial of trunk GEMV for ALL j; publish ----
        {
            float4 pa = {0.f, 0.f, 0.f, 0.f};
            const float* hrow = hts + rB * 33;
#pragma unroll 8
            for (int kl = 0; kl < 32; ++kl) {
                const float hv = hrow[kl];
                const float4 w4 = *(const float4*)&WtS[kl * 516 + jB];
                pa.x += hv * w4.x; pa.y += hv * w4.y;
                pa.z += hv * w4.z; pa.w += hv * w4.w;
            }
            const size_t pb = (size_t)(s & 1) * PHALF
                            + (size_t)(bp * 16 + g) * 2048 + rB * 512 + jB;
            union { float2 f; unsigned long long u; } q0, q1;
            q0.f = make_float2(pa.x, pa.y);
            q1.f = make_float2(pa.z, pa.w);
            __hip_atomic_store((unsigned long long*)&pP[pb], q0.u,
                               __ATOMIC_RELAXED, __HIP_MEMORY_SCOPE_AGENT);
            __hip_atomic_store((unsigned long long*)&pP[pb + 2], q1.u,
                               __ATOMIC_RELAXED, __HIP_MEMORY_SCOPE_AGENT);
        }
        __syncthreads();                       // drain all waves' stores

        // ---- single global barrier over the 16 same-bp blocks ----
        if (t == 0)
            __hip_atomic_store(&flags[(bp * 16 + g) * 32], (unsigned)(s + 1),
                               __ATOMIC_RELEASE, __HIP_MEMORY_SCOPE_AGENT);
        if (t < NSL)
            while (__hip_atomic_load(&flags[(bp * 16 + t) * 32],
                       __ATOMIC_RELAXED, __HIP_MEMORY_SCOPE_AGENT) < (unsigned)(s + 1))
                __builtin_amdgcn_s_sleep(1);
        __syncthreads();
        __builtin_amdgcn_sched_barrier(0);

        // ---- gather 16 partials, sum, tanh, LN stats ----
        float u0, u1, u2, u3;
        {
            float a0 = 0, a1 = 0, a2 = 0, a3 = 0;
            const unsigned long long* gp =
                (const unsigned long long*)(pP + (size_t)(s & 1) * PHALF);
            const int off = rB * 512 + jB;
#pragma unroll
            for (int gg = 0; gg < 16; ++gg) {
                const size_t base = ((size_t)(bp * 16 + gg) * 2048 + off) >> 1;
                unsigned long long v0 = __hip_atomic_load(&gp[base],
                                           __ATOMIC_RELAXED, __HIP_MEMORY_SCOPE_AGENT);
                unsigned long long v1 = __hip_atomic_load(&gp[base + 1],
                                           __ATOMIC_RELAXED, __HIP_MEMORY_SCOPE_AGENT);
                union { unsigned long long u; float2 f; } w0, w1;
                w0.u = v0; w1.u = v1;
                a0 += w0.f.x; a1 += w0.f.y; a2 += w1.f.x; a3 += w1.f.y;
            }
            u0 = tanhf(a0 + bt4.x); u1 = tanhf(a1 + bt4.y);
            u2 = tanhf(a2 + bt4.z); u3 = tanhf(a3 + bt4.w);
            float s1 = (u0 + u1) + (u2 + u3);
            float s2 = (u0 * u0 + u1 * u1) + (u2 * u2 + u3 * u3);
#pragma unroll
            for (int o = 1; o < 64; o <<= 1) {
                s1 += __shfl_xor(s1, o);
                s2 += __shfl_xor(s2, o);
            }
            if ((t & 63) == 0) red2[wid] = make_float2(s1, s2);
        }
        __syncthreads();

        // ---- apply LN, stage h_new into hb, write own hsB slice ----
        {
            const float2 A = red2[rB * 2], Bv = red2[rB * 2 + 1];
            const float mean = (A.x + Bv.x) * (1.0f / H_);
            const float var  = (A.y + Bv.y) * (1.0f / H_) - mean * mean;
            const float rs = rsqrtf(var + LN_EPS);
            float4 hn;
            hn.x = (u0 - mean) * rs * gm4.x + be4.x;
            hn.y = (u1 - mean) * rs * gm4.y + be4.y;
            hn.z = (u2 - mean) * rs * gm4.z + be4.z;
            hn.w = (u3 - mean) * rs * gm4.w + be4.w;
            *(float4*)&hb[rB * 516 + jB] = hn;
            if ((jB >> 5) == g) {
                ushort4 o;
                o.x = f2bf(hn.x); o.y = f2bf(hn.y);
                o.z = f2bf(hn.z); o.w = f2bf(hn.w);
                *(ushort4*)&hsB[((size_t)s * B_ + bp * 4 + rB) * H_ + jB] = o;
            }
        }
        __syncthreads();                       // hb ready for next phase A
    }
}

// ---------------- output GEMM (bf16 MFMA) ----------------
typedef __attribute__((ext_vector_type(8))) short short8;
typedef __attribute__((ext_vector_type(4))) float f32x4;

__global__ __launch_bounds__(256) void k_out_mfma(
        const unsigned short* __restrict__ hsB, const unsigned short* __restrict__ WoB,
        const float* __restrict__ b_out, float* __restrict__ y) {
    __shared__ unsigned short As[128 * 40];
    __shared__ unsigned short Bs[128 * 40];

    const int v0 = blockIdx.x * 128;
    const int m0 = blockIdx.y * 128;
    const int t = threadIdx.x;
    const int l = t & 63, wv = t >> 6;
    const int wm = wv >> 1, wn = wv & 1;

    f32x4 acc[4][4];
#pragma unroll
    for (int i = 0; i < 4; ++i)
#pragma unroll
        for (int jq = 0; jq < 4; ++jq)
            acc[i][jq] = (f32x4){0.f, 0.f, 0.f, 0.f};

    float bias[4];
#pragma unroll
    for (int ni = 0; ni < 4; ++ni) {
        int v = v0 + wn * 64 + ni * 16 + (l & 15);
        bias[ni] = (v < V_) ? b_out[v] : 0.f;
    }

    for (int k0 = 0; k0 < H_; k0 += 32) {
        __syncthreads();
        for (int c = t; c < 512; c += 256) {
            int row = c >> 2, seg = c & 3;
            *(uint4*)&As[row * 40 + seg * 8] =
                *(const uint4*)&hsB[(size_t)(m0 + row) * H_ + k0 + seg * 8];
            int vr = v0 + row; if (vr > V_ - 1) vr = V_ - 1;
            *(uint4*)&Bs[row * 40 + seg * 8] =
                *(const uint4*)&WoB[(size_t)vr * H_ + k0 + seg * 8];
        }
        __syncthreads();

        short8 af[4], bf[4];
#pragma unroll
        for (int i = 0; i < 4; ++i) {
            af[i] = *(short8*)&As[(wm * 64 + i * 16 + (l & 15)) * 40 + (l >> 4) * 8];
            bf[i] = *(short8*)&Bs[(wn * 64 + i * 16 + (l & 15)) * 40 + (l >> 4) * 8];
        }
#pragma unroll
        for (int mi = 0; mi < 4; ++mi)
#pragma unroll
            for (int ni = 0; ni < 4; ++ni)
                acc[mi][ni] = __builtin_amdgcn_mfma_f32_16x16x32_bf16(
                    af[mi], bf[ni], acc[mi][ni], 0, 0, 0);
    }

#pragma unroll
    for (int mi = 0; mi < 4; ++mi) {
#pragma unroll
        for (int ni = 0; ni < 4; ++ni) {
            int vcol = v0 + wn * 64 + ni * 16 + (l & 15);
            if (vcol < V_) {
#pragma unroll
                for (int p = 0; p < 4; ++p) {
                    int m = m0 + wm * 64 + mi * 16 + (l >> 4) * 4 + p;
                    int s = m >> 5, b = m & 31;
                    y[((size_t)b * S_ + s) * V_ + vcol] = acc[mi][ni][p] + bias[ni];
                }
            }
        }
    }
}

extern "C" void kernel_launch(void* const* d_in, const int* in_sizes, int n_in,
                              void* d_out, int out_size, void* d_ws, size_t ws_size,
                              hipStream_t stream) {
    const int*   x_idx = (const int*)d_in[0];
    const float* emb   = (const float*)d_in[1];
    const float* W_in  = (const float*)d_in[2];
    const float* b_in  = (const float*)d_in[3];
    const float* W_rec = (const float*)d_in[4];
    const float* b_rec = (const float*)d_in[5];
    const float* W_tr  = (const float*)d_in[6];
    const float* b_tr  = (const float*)d_in[7];
    const float* gamma = (const float*)d_in[8];
    const float* beta  = (const float*)d_in[9];
    const float* W_out = (const float*)d_in[10];
    const float* b_out = (const float*)d_in[11];
    float* y  = (float*)d_out;
    float* ws = (float*)d_ws;

    // workspace layout (float units), total ~15.29M floats = 61.2 MB
    float* WinT = ws;                                        // 131072
    float* Xp   = ws + 131072;                               // 8388608
    unsigned short* hsB = (unsigned short*)(ws + 8519680);   // 16384*512 bf16
    unsigned short* WoB = (unsigned short*)(ws + 12713984);  // 8000*512 bf16
    float* pP   = ws + 14761984;                             // 2*PHALF = 524288
    unsigned int* flags = (unsigned int*)(ws + 15286272);    // 128*32 u32

    (void)hipFuncSetAttribute((const void*)k_scan_1b,
                              hipFuncAttributeMaxDynamicSharedMemorySize,
                              LDSF * 4);

    dim3 tb(32, 8);
    k_transpose<<<dim3(I_ / 32, H_ / 32), tb, 0, stream>>>(W_in, WinT, H_, I_);

    k_cvt_bf16<<<1024, 256, 0, stream>>>(W_out, WoB, V_ * H_ / 4);

    k_embed_proj<<<(B_ * S_) / 8, 512, 0, stream>>>(x_idx, emb, WinT, b_in, Xp);

    hipMemsetAsync(flags, 0, NBLK * 32 * sizeof(unsigned int), stream);

    k_scan_1b<<<NBLK, 512, LDSF * 4, stream>>>(Xp, W_rec, b_rec, W_tr, b_tr,
                                               gamma, beta, pP, flags, hsB);

    k_out_mfma<<<dim3((V_ + 127) / 128, (B_ * S_) / 128), 256, 0, stream>>>(
        hsB, WoB, b_out, y);
}